// Round 8
// baseline (435.621 us; speedup 1.0000x reference)
//
#include <hip/hip_runtime.h>
#include <stdint.h>

#define NB 16
#define NC 256
#define NH 48
#define NW 160
#define HW (NH*NW)        // 7680
#define NP (NB*HW)        // 122880

static __device__ __forceinline__ unsigned short f2bf(float f){
  union { float f; uint32_t u; } v; v.f = f;
  uint32_t u = v.u;
  uint32_t r = (u + 0x7FFFu + ((u >> 16) & 1u)) >> 16;
  return (unsigned short)r;
}
static __device__ __forceinline__ float bf2f(unsigned short h){
  union { float f; uint32_t u; } v; v.u = ((uint32_t)h) << 16; return v.f;
}

typedef __attribute__((ext_vector_type(8))) short bf16x8;
typedef __attribute__((ext_vector_type(4))) float f32x4;

// ---- KW: Wb[o][c] = bf16(w_ext[o][1+c]) ------------------------------------
__global__ __launch_bounds__(256) void kw_conv(const float* __restrict__ w_ext,
                                               unsigned short* __restrict__ Wb){
  int idx = blockIdx.x * 256 + threadIdx.x;   // 65536
  int o = idx >> 8, c = idx & 255;
  Wb[idx] = f2bf(w_ext[o * 257 + 1 + c]);
}

// ---- KT: x[c][p] fp32 -> xT[p][c] bf16, + conv tap planes T[k][p] (fp32) ---
__global__ __launch_bounds__(256) void kt_stage(const float* __restrict__ x,
                                                const float* __restrict__ w_disp,
                                                unsigned short* __restrict__ xT,
                                                float* __restrict__ T){
  __shared__ float red[64 * 36];
  int p0  = blockIdx.x * 64;       // global pixel; 64 | 7680 so never crosses b
  int b   = p0 / HW;
  int hw0 = p0 - b * HW;           // local offset within image
  int t   = threadIdx.x;
  int sn  = t & 63;                // pixel within tile
  int skq = t >> 6;                // channel quarter (64 ch, contiguous)
  const float* xb = x + (size_t)b * NC * HW + hw0 + sn;
  unsigned short* xrow = xT + (size_t)(p0 + sn) * 256 + skq * 64;

  float acc[9];
  #pragma unroll
  for (int k = 0; k < 9; ++k) acc[k] = 0.f;

  for (int it = 0; it < 8; ++it){
    int c0 = skq * 64 + it * 8;
    const float* src = xb + (size_t)c0 * HW;
    float f[8];
    #pragma unroll
    for (int j = 0; j < 8; ++j) f[j] = src[(size_t)j * HW];  // 256B coalesced each
    #pragma unroll
    for (int j = 0; j < 8; ++j){
      const float* wd = w_disp + (c0 + j) * 9;               // uniform -> scalar
      #pragma unroll
      for (int k = 0; k < 9; ++k) acc[k] += f[j] * wd[k];
    }
    unsigned short h[8];
    #pragma unroll
    for (int j = 0; j < 8; ++j) h[j] = f2bf(f[j]);
    *(bf16x8*)(xrow + it * 8) = *(bf16x8*)h;   // 4 consecutive 16B stores/thread span 64B
  }

  #pragma unroll
  for (int k = 0; k < 9; ++k) red[sn * 36 + skq * 9 + k] = acc[k];
  __syncthreads();
  if (t < 64){
    #pragma unroll
    for (int k = 0; k < 9; ++k){
      float s = red[t * 36 + k] + red[t * 36 + 9 + k]
              + red[t * 36 + 18 + k] + red[t * 36 + 27 + k];
      T[(size_t)k * NP + p0 + t] = s;
    }
  }
}

// ---- KP: per-pixel grid params (wy, dlerp, off0, off1) ----------------------
__global__ __launch_bounds__(256) void kp_grid(
    const float* __restrict__ P2, const float* __restrict__ b_disp,
    const float* __restrict__ T, float4* __restrict__ pre)
{
  int p = blockIdx.x * 256 + threadIdx.x;   // 0..122879
  int b  = p / HW;
  int hw = p - b * HW;
  int y  = hw / NW;
  int xx = hw - y * NW;

  float d = 0.f;
  #pragma unroll
  for (int ky = 0; ky < 3; ++ky){
    int yy2 = y + ky - 1;
    if (yy2 < 0 || yy2 >= NH) continue;
    #pragma unroll
    for (int kx = 0; kx < 3; ++kx){
      int xx2 = xx + kx - 1;
      if (xx2 < 0 || xx2 >= NW) continue;
      d += T[(size_t)(ky * 3 + kx) * NP + b * HW + yy2 * NW + xx2];
    }
  }
  float th = tanhf(d + b_disp[0]);

  float fy = P2[b * 12 + 5] * 0.0625f;
  float cy = P2[b * 12 + 6] * 0.0625f;
  float Ty = P2[b * 12 + 7] * 0.0625f;

  float ysb   = fmaxf(1.535f * ((float)y - cy) / 1.765f, 0.f) * (1.f / 24.f);
  float ybase = -1.f + (float)y * (2.f / 47.f);
  float gy = ybase + ysb + 0.1f * th;
  float iy = fminf(fmaxf((gy + 1.f) * 0.5f * 47.f, 0.f), 47.f);
  float fiy0 = floorf(iy);
  float wy = iy - fiy0;
  int iy0 = (int)fiy0;
  int iy1 = min(iy0 + 1, 47);

  float inv_den = 1.f / (fabsf(fy * 1.65f + Ty) + 1e-10f);
  float dr0 = fmaxf(fy * 0.54f * ((float)iy0 - cy) * inv_den, 0.f);
  float dr1 = fmaxf(fy * 0.54f * ((float)iy1 - cy) * inv_den, 0.f);
  float dlerp = (1.f - wy) * dr0 + wy * dr1;

  float4 pr;
  pr.x = wy; pr.y = dlerp;
  pr.z = __int_as_float(iy0 * NW + xx);
  pr.w = __int_as_float(iy1 * NW + xx);
  pre[p] = pr;
}

// ---- KB: fused sample-GEMM-residual. out[o][p] = relu(x[o][p] + al*(
//          sum_c Wb[o][c]*lerp(xT rows)[c] + w0[o]*dlerp + b_ext[o])) --------
__global__ __launch_bounds__(256) void kb_fused(
    const unsigned short* __restrict__ Wb,   // [256][256] bf16 k-contig
    const unsigned short* __restrict__ xT,   // [NP][256]  bf16 k-contig
    const float4* __restrict__ pre,          // [NP] (wy, dlerp, off0, off1)
    const float* __restrict__ x,
    const float* __restrict__ w_ext,
    const float* __restrict__ b_ext,
    const float* __restrict__ alpha,
    float* __restrict__ out)
{
  int bx = blockIdx.x;            // 1920 = 16 b * 120 nt
  int b  = bx / 120;
  int nt = bx - b * 120;
  int hw0 = nt * 64;

  int tid  = threadIdx.x;
  int lane = tid & 63;
  int w    = tid >> 6;            // wave 0..3 = m-quarter
  int l15 = lane & 15;
  int lq  = lane >> 4;

  const unsigned short* Abase = Wb + ((size_t)(w * 64 + l15)) * 256 + lq * 8;

  // per-ni sampling params (lane-indexed pixel n = ni*16 + l15)
  size_t rowT = (size_t)b * HW;
  float wyv[4], w1v[4], dlv[4];
  const unsigned short* r0p[4];
  const unsigned short* r1p[4];
  #pragma unroll
  for (int ni = 0; ni < 4; ++ni){
    int n = ni * 16 + l15;
    float4 pr = pre[rowT + hw0 + n];
    wyv[ni] = pr.x; w1v[ni] = 1.f - pr.x; dlv[ni] = pr.y;
    int o0 = __float_as_int(pr.z);
    int o1 = __float_as_int(pr.w);
    r0p[ni] = xT + (rowT + o0) * 256 + lq * 8;
    r1p[ni] = xT + (rowT + o1) * 256 + lq * 8;
  }

  f32x4 zero = {0.f, 0.f, 0.f, 0.f};
  f32x4 acc[4][4];
  #pragma unroll
  for (int mi = 0; mi < 4; ++mi)
    #pragma unroll
    for (int ni = 0; ni < 4; ++ni) acc[mi][ni] = zero;

  for (int ks = 0; ks < 8; ++ks){
    bf16x8 af[4], bg[4];
    #pragma unroll
    for (int mi = 0; mi < 4; ++mi)
      af[mi] = *(const bf16x8*)(Abase + (size_t)(mi * 16) * 256 + ks * 32);
    #pragma unroll
    for (int ni = 0; ni < 4; ++ni){
      const unsigned short* s0 = r0p[ni] + ks * 32;
      const unsigned short* s1 = r1p[ni] + ks * 32;
      bf16x8 u0 = *(const bf16x8*)s0;
      bf16x8 u1 = *(const bf16x8*)s1;
      unsigned short h[8];
      #pragma unroll
      for (int e = 0; e < 8; ++e){
        float a0 = bf2f((unsigned short)u0[e]);
        float a1 = bf2f((unsigned short)u1[e]);
        h[e] = f2bf(w1v[ni] * a0 + wyv[ni] * a1);
      }
      bg[ni] = *(bf16x8*)h;
    }
    #pragma unroll
    for (int mi = 0; mi < 4; ++mi)
      #pragma unroll
      for (int ni = 0; ni < 4; ++ni)
        acc[mi][ni] = __builtin_amdgcn_mfma_f32_16x16x32_bf16(af[mi], bg[ni], acc[mi][ni], 0, 0, 0);
  }

  // epilogue: C/D layout col=l15 (n), row=lq*4+r (m=o)
  float al = alpha[0];
  #pragma unroll
  for (int mi = 0; mi < 4; ++mi){
    int obase = w * 64 + mi * 16 + lq * 4;
    #pragma unroll
    for (int ni = 0; ni < 4; ++ni){
      int n = ni * 16 + l15;
      size_t gp = ((size_t)(b * NC + obase)) * HW + hw0 + n;
      #pragma unroll
      for (int r = 0; r < 4; ++r){
        int o = obase + r;
        float val = acc[mi][ni][r] + w_ext[o * 257] * dlv[ni] + b_ext[o];
        float res = x[gp + (size_t)r * HW] + al * val;
        out[gp + (size_t)r * HW] = fmaxf(res, 0.f);
      }
    }
  }
}

// ---------------------------------------------------------------------------
extern "C" void kernel_launch(void* const* d_in, const int* in_sizes, int n_in,
                              void* d_out, int out_size, void* d_ws, size_t ws_size,
                              hipStream_t stream) {
  const float* features = (const float*)d_in[0];
  const float* P2       = (const float*)d_in[1];
  const float* w_disp   = (const float*)d_in[2];
  const float* b_disp   = (const float*)d_in[3];
  const float* w_ext    = (const float*)d_in[4];
  const float* b_ext    = (const float*)d_in[5];
  const float* alpha    = (const float*)d_in[6];
  float* out = (float*)d_out;

  char* ws = (char*)d_ws;
  const size_t xT_bytes  = (size_t)NP * 256 * 2;   // 62,914,560
  const size_t T_bytes   = (size_t)9 * NP * 4;     //  4,423,680
  const size_t pre_bytes = (size_t)NP * 16;        //  1,966,080
  unsigned short* xT  = (unsigned short*)ws;
  float*          T   = (float*)(ws + xT_bytes);
  float4*         pre = (float4*)(ws + xT_bytes + T_bytes);
  unsigned short* Wb  = (unsigned short*)(ws + xT_bytes + T_bytes + pre_bytes);

  hipLaunchKernelGGL(kw_conv,  dim3(256),  dim3(256), 0, stream, w_ext, Wb);
  hipLaunchKernelGGL(kt_stage, dim3(1920), dim3(256), 0, stream, features, w_disp, xT, T);
  hipLaunchKernelGGL(kp_grid,  dim3(480),  dim3(256), 0, stream, P2, b_disp, T, pre);
  hipLaunchKernelGGL(kb_fused, dim3(1920), dim3(256), 0, stream,
                     Wb, xT, pre, features, w_ext, b_ext, alpha, out);
}